// Round 4
// baseline (384.370 us; speedup 1.0000x reference)
//
#include <hip/hip_runtime.h>

#define IN_C 128
#define OUT_C 64

// ---------------- CSR build ----------------

__global__ __launch_bounds__(256) void k_count(const int* __restrict__ dst,
                                               int* __restrict__ cnt, int E) {
    int e = blockIdx.x * 256 + threadIdx.x;
    if (e < E) atomicAdd(&cnt[dst[e]], 1);
}

// Wave-level scan allocation: ONE atomic per 64 nodes (not per node).
__global__ __launch_bounds__(256) void k_alloc(const int* __restrict__ cnt,
                                               int* __restrict__ row_start,
                                               int* __restrict__ cursor,
                                               float* __restrict__ dinv,
                                               int* __restrict__ total, int N) {
    int i    = blockIdx.x * 256 + threadIdx.x;
    int lane = threadIdx.x & 63;
    int c = (i < N) ? cnt[i] : 0;
    // inclusive scan across the wave
    int scan = c;
    #pragma unroll
    for (int d = 1; d < 64; d <<= 1) {
        int t = __shfl_up(scan, d);
        if (lane >= d) scan += t;
    }
    int wave_total = __shfl(scan, 63);
    int base = 0;
    if (lane == 63) base = atomicAdd(total, wave_total);
    base = __shfl(base, 63);
    if (i < N) {
        int s = base + scan - c;     // exclusive prefix within wave
        row_start[i] = s;
        cursor[i]    = s;
        dinv[i] = 1.0f / sqrtf((float)(c + 1));   // +1 self-loop
    }
}

__global__ __launch_bounds__(256) void k_fill(const int* __restrict__ src,
                                              const int* __restrict__ dst,
                                              int* __restrict__ cursor,
                                              int* __restrict__ col, int E) {
    int e = blockIdx.x * 256 + threadIdx.x;
    if (e < E) {
        int p = atomicAdd(&cursor[dst[e]], 1);
        col[p] = src[e];
    }
}

// ---------------- propagation core: wave-per-node gather ----------------
// acc = dinv[i]^2 * h[i] + sum_j dinv[i]*dinv[j]*h[j]
// Returns per-lane float2 (channels 2*lane, 2*lane+1).

__device__ __forceinline__ float2 gather_row(const float* __restrict__ hin,
                                             const int* __restrict__ col,
                                             const float* __restrict__ dinv,
                                             int s, int c, float di, int i, int lane) {
    const float2* xr = (const float2*)(hin + (size_t)i * IN_C);
    float2 v = xr[lane];
    float2 acc0, acc1;
    acc0.x = di * di * v.x;
    acc0.y = di * di * v.y;
    acc1.x = 0.f;
    acc1.y = 0.f;
    for (int base = 0; base < c; base += 64) {
        int rem = min(64, c - base);
        int   myj = 0;
        float myw = 0.f;
        if (lane < rem) { myj = col[s + base + lane]; myw = dinv[myj]; }
        int k = 0;
        // 4-wide unroll: independent 512B gathers issued together for ILP
        for (; k + 3 < rem; k += 4) {
            int j0 = __shfl(myj, k),     j1 = __shfl(myj, k + 1);
            int j2 = __shfl(myj, k + 2), j3 = __shfl(myj, k + 3);
            float w0 = di * __shfl(myw, k),     w1 = di * __shfl(myw, k + 1);
            float w2 = di * __shfl(myw, k + 2), w3 = di * __shfl(myw, k + 3);
            float2 u0 = ((const float2*)(hin + (size_t)j0 * IN_C))[lane];
            float2 u1 = ((const float2*)(hin + (size_t)j1 * IN_C))[lane];
            float2 u2 = ((const float2*)(hin + (size_t)j2 * IN_C))[lane];
            float2 u3 = ((const float2*)(hin + (size_t)j3 * IN_C))[lane];
            acc0.x += w0 * u0.x; acc0.y += w0 * u0.y;
            acc1.x += w1 * u1.x; acc1.y += w1 * u1.y;
            acc0.x += w2 * u2.x; acc0.y += w2 * u2.y;
            acc1.x += w3 * u3.x; acc1.y += w3 * u3.y;
        }
        for (; k < rem; ++k) {
            int   j = __shfl(myj, k);
            float w = di * __shfl(myw, k);
            float2 u = ((const float2*)(hin + (size_t)j * IN_C))[lane];
            acc0.x += w * u.x;
            acc0.y += w * u.y;
        }
    }
    acc0.x += acc1.x;
    acc0.y += acc1.y;
    return acc0;
}

__global__ __launch_bounds__(256) void k_hop(const float* __restrict__ hin,
                                             const int* __restrict__ col,
                                             const int* __restrict__ row_start,
                                             const int* __restrict__ cnt,
                                             const float* __restrict__ dinv,
                                             float* __restrict__ hout, int N) {
    int lane = threadIdx.x & 63;
    int wid  = (blockIdx.x * blockDim.x + threadIdx.x) >> 6;
    int nw   = (gridDim.x * blockDim.x) >> 6;
    for (int i = wid; i < N; i += nw) {
        float2 acc = gather_row(hin, col, dinv, row_start[i], cnt[i], dinv[i], i, lane);
        ((float2*)(hout + (size_t)i * IN_C))[lane] = acc;
    }
}

// hop2 fused with terminal linear: out[i][o] = b[o] + sum_c h2[i][c]*W[o][c], lane == o
__global__ __launch_bounds__(256) void k_hop_linear(const float* __restrict__ hin,
                                                    const int* __restrict__ col,
                                                    const int* __restrict__ row_start,
                                                    const int* __restrict__ cnt,
                                                    const float* __restrict__ dinv,
                                                    const float* __restrict__ W,
                                                    const float* __restrict__ b,
                                                    float* __restrict__ out, int N) {
    __shared__ float Wt[IN_C][OUT_C];   // 32 KiB, Wt[c][o] = W[o][c]
    for (int idx = threadIdx.x; idx < IN_C * OUT_C; idx += 256) {
        int o = idx >> 7;
        int c = idx & 127;
        Wt[c][o] = W[idx];
    }
    __syncthreads();

    int lane = threadIdx.x & 63;
    int wid  = (blockIdx.x * blockDim.x + threadIdx.x) >> 6;
    int nw   = (gridDim.x * blockDim.x) >> 6;
    float bias = b[lane];

    for (int i = wid; i < N; i += nw) {
        float2 acc = gather_row(hin, col, dinv, row_start[i], cnt[i], dinv[i], i, lane);
        float o = bias;
        #pragma unroll
        for (int c2 = 0; c2 < 64; ++c2) {
            float vx = __shfl(acc.x, c2);   // channel 2*c2
            float vy = __shfl(acc.y, c2);   // channel 2*c2+1
            o += vx * Wt[2 * c2][lane] + vy * Wt[2 * c2 + 1][lane];
        }
        out[(size_t)i * OUT_C + lane] = o;
    }
}

// ---------------- launcher ----------------

extern "C" void kernel_launch(void* const* d_in, const int* in_sizes, int n_in,
                              void* d_out, int out_size, void* d_ws, size_t ws_size,
                              hipStream_t stream) {
    const float* x  = (const float*)d_in[0];
    const int*   ei = (const int*)d_in[1];
    const float* W  = (const float*)d_in[2];
    const float* b  = (const float*)d_in[3];
    float* out = (float*)d_out;

    int N = in_sizes[0] / IN_C;      // 65536
    int E = in_sizes[1] / 2;         // 655360
    const int* src = ei;
    const int* dst = ei + E;

    // workspace layout (bytes)
    size_t off_cnt   = 0;                       // N i32
    size_t off_total = off_cnt + (size_t)N * 4; // 1 i32 (memset with cnt)
    size_t off_rs    = off_total + 256;         // N i32
    size_t off_cur   = off_rs + (size_t)N * 4;  // N i32
    size_t off_dinv  = off_cur + (size_t)N * 4; // N f32
    size_t off_col   = off_dinv + (size_t)N * 4;// E i32
    size_t off_h1    = (off_col + (size_t)E * 4 + 255) & ~(size_t)255; // N*IN_C f32
    size_t need      = off_h1 + (size_t)N * IN_C * 4;
    if (ws_size < need) return;   // refuse to scribble OOB (would crash the container)

    char* ws = (char*)d_ws;
    int*   cnt       = (int*)(ws + off_cnt);
    int*   total     = (int*)(ws + off_total);
    int*   row_start = (int*)(ws + off_rs);
    int*   cursor    = (int*)(ws + off_cur);
    float* dinv      = (float*)(ws + off_dinv);
    int*   col       = (int*)(ws + off_col);
    float* h1        = (float*)(ws + off_h1);

    hipMemsetAsync(ws, 0, off_total + 4, stream);   // cnt + total

    int ge = (E + 255) / 256;
    int gn = (N + 255) / 256;
    k_count<<<ge, 256, 0, stream>>>(dst, cnt, E);
    k_alloc<<<gn, 256, 0, stream>>>(cnt, row_start, cursor, dinv, total, N);
    k_fill <<<ge, 256, 0, stream>>>(src, dst, cursor, col, E);

    k_hop       <<<2048, 256, 0, stream>>>(x,  col, row_start, cnt, dinv, h1, N);
    k_hop_linear<<<2048, 256, 0, stream>>>(h1, col, row_start, cnt, dinv, W, b, out, N);
}

// Round 6
// 341.819 us; speedup vs baseline: 1.1245x; 1.1245x over previous
//
#include <hip/hip_runtime.h>

#define IN_C 128
#define OUT_C 64
#define PAD 8            // degree padded to multiple of 8 -> fixed 8-deep gather groups
typedef long long ll;

// ---------------- CSR build ----------------

__global__ __launch_bounds__(256) void k_count(const int* __restrict__ dst,
                                               int* __restrict__ cnt, int E) {
    int e = blockIdx.x * 256 + threadIdx.x;
    if (e < E) atomicAdd(&cnt[dst[e]], 1);
}

// Allocate padded slot ranges (one atomic per wave via scan), write meta+dinv,
// convert cnt[] into cursor[], and pre-fill pad slots with (col=i, w=0).
__global__ __launch_bounds__(256) void k_alloc(int* __restrict__ cnt_cursor,
                                               int4* __restrict__ meta,
                                               float* __restrict__ dinv,
                                               int2* __restrict__ wcol,
                                               int* __restrict__ total, int N) {
    int i    = blockIdx.x * 256 + threadIdx.x;
    int lane = threadIdx.x & 63;
    int c  = (i < N) ? cnt_cursor[i] : 0;
    int c8 = (c + PAD - 1) & ~(PAD - 1);
    int scan = c8;                       // inclusive wave scan
    #pragma unroll
    for (int d = 1; d < 64; d <<= 1) {
        int t = __shfl_up(scan, d);
        if (lane >= d) scan += t;
    }
    int wave_total = __shfl(scan, 63);
    int base = 0;
    if (lane == 63) base = atomicAdd(total, wave_total);
    base = __shfl(base, 63);
    if (i < N) {
        int s = base + scan - c8;        // exclusive prefix
        float dv = 1.0f / sqrtf((float)(c + 1));   // +1 self-loop
        meta[i] = make_int4(s, c8, __float_as_int(dv), 0);
        dinv[i] = dv;
        cnt_cursor[i] = s;               // becomes fill cursor
        for (int p = s + c; p < s + c8; ++p)       // <=7 pad slots
            wcol[p] = make_int2(i, 0);   // w bits 0 == 0.0f
    }
}

// Fill slots with (src, precomputed weight dinv[src]*dinv[dst]).
__global__ __launch_bounds__(256) void k_fill(const int* __restrict__ src,
                                              const int* __restrict__ dst,
                                              int* __restrict__ cursor,
                                              const float* __restrict__ dinv,
                                              int2* __restrict__ wcol, int E) {
    int e = blockIdx.x * 256 + threadIdx.x;
    if (e < E) {
        int s = src[e], d = dst[e];
        int p = atomicAdd(&cursor[d], 1);
        float w = dinv[s] * dinv[d];
        wcol[p] = make_int2(s, __float_as_int(w));
    }
}

// ---------------- gather core: 8-deep MLP, weights pre-baked ----------------
// acc = di^2 * h[i] + sum_slots w * h[col];  pad slots have w=0.

__device__ __forceinline__ float2 gather_node(const float* __restrict__ hin,
                                              const int2* __restrict__ wcol,
                                              int s, int c8, float di, int i, int lane) {
    float2 v = ((const float2*)(hin + (ll)i * IN_C))[lane];
    float2 acc0 = make_float2(di * di * v.x, di * di * v.y);
    float2 acc1 = make_float2(0.f, 0.f);
    for (int base = 0; base < c8; base += 64) {
        int nb = min(64, c8 - base);                 // multiple of 8
        int2 slot = wcol[s + base + lane];           // capacity has +64 guard slots
        for (int g = 0; g < nb; g += 8) {
            // broadcast 8 (j,w) to SGPRs; 8 independent 512B row gathers in flight
            int   j0 = __builtin_amdgcn_readlane(slot.x, g + 0);
            int   j1 = __builtin_amdgcn_readlane(slot.x, g + 1);
            int   j2 = __builtin_amdgcn_readlane(slot.x, g + 2);
            int   j3 = __builtin_amdgcn_readlane(slot.x, g + 3);
            int   j4 = __builtin_amdgcn_readlane(slot.x, g + 4);
            int   j5 = __builtin_amdgcn_readlane(slot.x, g + 5);
            int   j6 = __builtin_amdgcn_readlane(slot.x, g + 6);
            int   j7 = __builtin_amdgcn_readlane(slot.x, g + 7);
            float w0 = __int_as_float(__builtin_amdgcn_readlane(slot.y, g + 0));
            float w1 = __int_as_float(__builtin_amdgcn_readlane(slot.y, g + 1));
            float w2 = __int_as_float(__builtin_amdgcn_readlane(slot.y, g + 2));
            float w3 = __int_as_float(__builtin_amdgcn_readlane(slot.y, g + 3));
            float w4 = __int_as_float(__builtin_amdgcn_readlane(slot.y, g + 4));
            float w5 = __int_as_float(__builtin_amdgcn_readlane(slot.y, g + 5));
            float w6 = __int_as_float(__builtin_amdgcn_readlane(slot.y, g + 6));
            float w7 = __int_as_float(__builtin_amdgcn_readlane(slot.y, g + 7));
            float2 u0 = ((const float2*)(hin + (ll)j0 * IN_C))[lane];
            float2 u1 = ((const float2*)(hin + (ll)j1 * IN_C))[lane];
            float2 u2 = ((const float2*)(hin + (ll)j2 * IN_C))[lane];
            float2 u3 = ((const float2*)(hin + (ll)j3 * IN_C))[lane];
            float2 u4 = ((const float2*)(hin + (ll)j4 * IN_C))[lane];
            float2 u5 = ((const float2*)(hin + (ll)j5 * IN_C))[lane];
            float2 u6 = ((const float2*)(hin + (ll)j6 * IN_C))[lane];
            float2 u7 = ((const float2*)(hin + (ll)j7 * IN_C))[lane];
            acc0.x += w0 * u0.x; acc0.y += w0 * u0.y;
            acc1.x += w1 * u1.x; acc1.y += w1 * u1.y;
            acc0.x += w2 * u2.x; acc0.y += w2 * u2.y;
            acc1.x += w3 * u3.x; acc1.y += w3 * u3.y;
            acc0.x += w4 * u4.x; acc0.y += w4 * u4.y;
            acc1.x += w5 * u5.x; acc1.y += w5 * u5.y;
            acc0.x += w6 * u6.x; acc0.y += w6 * u6.y;
            acc1.x += w7 * u7.x; acc1.y += w7 * u7.y;
        }
    }
    acc0.x += acc1.x; acc0.y += acc1.y;
    return acc0;
}

__global__ __launch_bounds__(256) void k_hop(const float* __restrict__ hin,
                                             const int2* __restrict__ wcol,
                                             const int4* __restrict__ meta,
                                             float* __restrict__ hout, int N) {
    int lane = threadIdx.x & 63;
    int w0 = (blockIdx.x * blockDim.x + threadIdx.x) >> 6;
    int nw = (gridDim.x * blockDim.x) >> 6;
    for (int ii = w0; ii < N; ii += nw) {
        int i = __builtin_amdgcn_readfirstlane(ii);   // scalarize: meta via s_load
        int4 m = meta[i];
        float di = __int_as_float(m.z);
        float2 acc = gather_node(hin, wcol, m.x, m.y, di, i, lane);
        ((float2*)(hout + (ll)i * IN_C))[lane] = acc;
    }
}

// hop2 fused with terminal linear. Wt2[c2][o] = {W[o][2c2], W[o][2c2+1]},
// XOR-swizzled so both the transpose-write and the read are conflict-free.
__global__ __launch_bounds__(256) void k_hop_linear(const float* __restrict__ hin,
                                                    const int2* __restrict__ wcol,
                                                    const int4* __restrict__ meta,
                                                    const float* __restrict__ W,
                                                    const float* __restrict__ b,
                                                    float* __restrict__ out, int N) {
    __shared__ float2 Wt2[64][64];                   // 32 KiB
    const float2* W2 = (const float2*)W;
    for (int idx = threadIdx.x; idx < 4096; idx += 256) {
        int o = idx >> 6, c2 = idx & 63;
        Wt2[c2][o ^ (c2 & 31)] = W2[idx];            // coalesced read, ~2-way (free) write
    }
    __syncthreads();

    int lane = threadIdx.x & 63;
    int w0 = (blockIdx.x * blockDim.x + threadIdx.x) >> 6;
    int nw = (gridDim.x * blockDim.x) >> 6;
    float bias = b[lane];

    for (int ii = w0; ii < N; ii += nw) {
        int i = __builtin_amdgcn_readfirstlane(ii);
        int4 m = meta[i];
        float di = __int_as_float(m.z);
        float2 acc = gather_node(hin, wcol, m.x, m.y, di, i, lane);
        float r = bias;                              // lane == output channel
        #pragma unroll
        for (int c2 = 0; c2 < 64; ++c2) {
            float hx = __shfl(acc.x, c2);            // channel 2*c2   (readlane imm)
            float hy = __shfl(acc.y, c2);            // channel 2*c2+1
            float2 wp = Wt2[c2][lane ^ (c2 & 31)];   // swizzle-matched, conflict-free
            r += hx * wp.x + hy * wp.y;
        }
        out[(ll)i * OUT_C + lane] = r;
    }
}

// ---------------- launcher ----------------

extern "C" void kernel_launch(void* const* d_in, const int* in_sizes, int n_in,
                              void* d_out, int out_size, void* d_ws, size_t ws_size,
                              hipStream_t stream) {
    const float* x  = (const float*)d_in[0];
    const int*   ei = (const int*)d_in[1];
    const float* W  = (const float*)d_in[2];
    const float* b  = (const float*)d_in[3];
    float* out = (float*)d_out;

    int N = in_sizes[0] / IN_C;      // 65536
    int E = in_sizes[1] / 2;         // 655360
    const int* src = ei;
    const int* dst = ei + E;

    // workspace layout
    size_t cap_slots = (size_t)E + (size_t)PAD * N + 64;     // padded CSR + read guard
    size_t off_cnt   = 0;                                     // N i32 (cnt -> cursor)
    size_t off_total = (size_t)N * 4;                         // 1 i32
    size_t off_meta  = ((off_total + 4 + 255) & ~(size_t)255);// N int4
    size_t off_dinv  = off_meta + (size_t)N * 16;             // N f32
    size_t off_wcol  = off_dinv + (size_t)N * 4;              // cap_slots int2
    size_t off_h1    = ((off_wcol + cap_slots * 8 + 255) & ~(size_t)255);
    size_t need      = off_h1 + (size_t)N * IN_C * 4;
    if (ws_size < need) return;      // refuse to scribble OOB

    char* ws = (char*)d_ws;
    int*   cnt_cursor = (int*)(ws + off_cnt);
    int*   total      = (int*)(ws + off_total);
    int4*  meta       = (int4*)(ws + off_meta);
    float* dinv       = (float*)(ws + off_dinv);
    int2*  wcol       = (int2*)(ws + off_wcol);
    float* h1         = (float*)(ws + off_h1);

    hipMemsetAsync(ws, 0, off_total + 4, stream);   // cnt + total

    int ge = (E + 255) / 256;
    int gn = (N + 255) / 256;
    k_count<<<ge, 256, 0, stream>>>(dst, cnt_cursor, E);
    k_alloc<<<gn, 256, 0, stream>>>(cnt_cursor, meta, dinv, wcol, total, N);
    k_fill <<<ge, 256, 0, stream>>>(src, dst, cnt_cursor, dinv, wcol, E);

    k_hop       <<<4096, 256, 0, stream>>>(x,  wcol, meta, h1, N);
    k_hop_linear<<<2048, 256, 0, stream>>>(h1, wcol, meta, W, b, out, N);
}

// Round 11
// 314.829 us; speedup vs baseline: 1.2209x; 1.0857x over previous
//
#include <hip/hip_runtime.h>

#define IN_C 128
#define OUT_C 64
#define PAD 8            // degree padded to multiple of 8 -> fixed 8-deep gather groups
typedef long long ll;

// ---------------- CSR build ----------------

__global__ __launch_bounds__(256) void k_count(const int* __restrict__ dst,
                                               int* __restrict__ cnt, int E) {
    int e = blockIdx.x * 256 + threadIdx.x;
    if (e < E) atomicAdd(&cnt[dst[e]], 1);
}

// Allocate padded slot ranges (one atomic per wave via scan), write meta+dinv,
// convert cnt[] into cursor[], and pre-fill pad slots with (col=i, w=0).
__global__ __launch_bounds__(256) void k_alloc(int* __restrict__ cnt_cursor,
                                               int4* __restrict__ meta,
                                               float* __restrict__ dinv,
                                               int2* __restrict__ wcol,
                                               int* __restrict__ total, int N) {
    int i    = blockIdx.x * 256 + threadIdx.x;
    int lane = threadIdx.x & 63;
    int c  = (i < N) ? cnt_cursor[i] : 0;
    int c8 = (c + PAD - 1) & ~(PAD - 1);
    int scan = c8;                       // inclusive wave scan
    #pragma unroll
    for (int d = 1; d < 64; d <<= 1) {
        int t = __shfl_up(scan, d);
        if (lane >= d) scan += t;
    }
    int wave_total = __shfl(scan, 63);
    int base = 0;
    if (lane == 63) base = atomicAdd(total, wave_total);
    base = __shfl(base, 63);
    if (i < N) {
        int s = base + scan - c8;        // exclusive prefix
        float dv = 1.0f / sqrtf((float)(c + 1));   // +1 self-loop
        meta[i] = make_int4(s, c8, __float_as_int(dv), 0);
        dinv[i] = dv;
        cnt_cursor[i] = s;               // becomes fill cursor
        for (int p = s + c; p < s + c8; ++p)       // <=7 pad slots
            wcol[p] = make_int2(i, 0);   // w bits 0 == 0.0f; row i is L1-hot -> cheap
    }
}

// Fill slots with (src, precomputed weight dinv[src]*dinv[dst]).
__global__ __launch_bounds__(256) void k_fill(const int* __restrict__ src,
                                              const int* __restrict__ dst,
                                              int* __restrict__ cursor,
                                              const float* __restrict__ dinv,
                                              int2* __restrict__ wcol, int E) {
    int e = blockIdx.x * 256 + threadIdx.x;
    if (e < E) {
        int s = src[e], d = dst[e];
        int p = atomicAdd(&cursor[d], 1);
        float w = dinv[s] * dinv[d];
        wcol[p] = make_int2(s, __float_as_int(w));
    }
}

// ---------------- GEMM first: y0 = x @ W.T  (no bias; bias added after hops) ----------------
// (S^2 x) W^T == S^2 (x W^T): the linear commutes with propagation.

__global__ __launch_bounds__(256) void k_gemm(const float* __restrict__ x,
                                              const float* __restrict__ W,
                                              float* __restrict__ y0, int N) {
    __shared__ float2 Wt2[64][64];                   // Wt2[c2][o] = {W[o][2c2], W[o][2c2+1]}
    const float2* W2 = (const float2*)W;
    for (int idx = threadIdx.x; idx < 4096; idx += 256) {
        int o = idx >> 6, c2 = idx & 63;
        Wt2[c2][o ^ (c2 & 31)] = W2[idx];            // swizzled: conflict-free both sides
    }
    __syncthreads();

    int lane = threadIdx.x & 63;
    int w0 = (blockIdx.x * blockDim.x + threadIdx.x) >> 6;
    int nw = (gridDim.x * blockDim.x) >> 6;
    for (int r = w0; r < N; r += nw) {
        float2 v = ((const float2*)(x + (ll)r * IN_C))[lane];   // channels 2l, 2l+1
        float acc = 0.f;
        #pragma unroll
        for (int c2 = 0; c2 < 64; ++c2) {
            float hx = __shfl(v.x, c2);              // x[r, 2c2]   (uniform lane -> readlane)
            float hy = __shfl(v.y, c2);              // x[r, 2c2+1]
            float2 wp = Wt2[c2][lane ^ (c2 & 31)];
            acc += hx * wp.x + hy * wp.y;
        }
        y0[(ll)r * OUT_C + lane] = acc;              // lane == output channel, coalesced
    }
}

// ---------------- 64-channel gather core ----------------
// acc = di^2 * h[i][lane] + sum_slots w * h[col][lane];  pad slots have w=0.
// One row = 256 B = exactly one float/lane wave transaction.

template<int G>
__device__ __forceinline__ void g8(float& a0, float& a1, const float* __restrict__ hin,
                                   int2 slot, int lane) {
    int j[8]; float w[8];
    #pragma unroll
    for (int k = 0; k < 8; ++k) {
        j[k] = __builtin_amdgcn_readlane(slot.x, G + k);                    // SGPR
        w[k] = __int_as_float(__builtin_amdgcn_readlane(slot.y, G + k));    // SGPR
    }
    float u[8];
    #pragma unroll
    for (int k = 0; k < 8; ++k) u[k] = hin[(ll)j[k] * OUT_C + lane];        // 8 loads in flight
    #pragma unroll
    for (int k = 0; k < 8; ++k) { if (k & 1) a1 += w[k] * u[k]; else a0 += w[k] * u[k]; }
}

__device__ __forceinline__ void g8dyn(float& a0, float& a1, const float* __restrict__ hin,
                                      int2 slot, int g, int lane) {
    int j[8]; float w[8];
    #pragma unroll
    for (int k = 0; k < 8; ++k) {
        j[k] = __builtin_amdgcn_readlane(slot.x, g + k);
        w[k] = __int_as_float(__builtin_amdgcn_readlane(slot.y, g + k));
    }
    float u[8];
    #pragma unroll
    for (int k = 0; k < 8; ++k) u[k] = hin[(ll)j[k] * OUT_C + lane];
    #pragma unroll
    for (int k = 0; k < 8; ++k) { if (k & 1) a1 += w[k] * u[k]; else a0 += w[k] * u[k]; }
}

__device__ __forceinline__ float gather64(const float* __restrict__ hin,
                                          const int2* __restrict__ wcol,
                                          int s, int c8, float di, int i, int lane) {
    float v  = hin[(ll)i * OUT_C + lane];
    float a0 = di * di * v, a1 = 0.f;
    // c8 is wave-uniform -> scalar branch into straight-line code (97% of nodes)
    if (c8 == 8) {
        int2 sl = wcol[s + lane];                    // +64 guard slots cover lanes 8..63
        g8<0>(a0, a1, hin, sl, lane);
    } else if (c8 == 16) {
        int2 sl = wcol[s + lane];
        g8<0>(a0, a1, hin, sl, lane);                // all 16 gathers independent,
        g8<8>(a0, a1, hin, sl, lane);                // issued back-to-back
    } else if (c8 > 0) {
        for (int base = 0; base < c8; base += 64) {
            int nb = min(64, c8 - base);
            int2 sl = wcol[s + base + lane];
            for (int g = 0; g < nb; g += 8) g8dyn(a0, a1, hin, sl, g, lane);
        }
    }
    return a0 + a1;
}

__global__ __launch_bounds__(256) void k_hop64(const float* __restrict__ hin,
                                               const int2* __restrict__ wcol,
                                               const int4* __restrict__ meta,
                                               float* __restrict__ hout, int N) {
    int lane = threadIdx.x & 63;
    int w0 = (blockIdx.x * blockDim.x + threadIdx.x) >> 6;
    int nw = (gridDim.x * blockDim.x) >> 6;
    for (int ii = w0; ii < N; ii += nw) {
        int i = __builtin_amdgcn_readfirstlane(ii);
        int4 m = meta[i];
        float acc = gather64(hin, wcol, m.x, m.y, __int_as_float(m.z), i, lane);
        hout[(ll)i * OUT_C + lane] = acc;
    }
}

__global__ __launch_bounds__(256) void k_hop64_bias(const float* __restrict__ hin,
                                                    const int2* __restrict__ wcol,
                                                    const int4* __restrict__ meta,
                                                    const float* __restrict__ b,
                                                    float* __restrict__ out, int N) {
    int lane = threadIdx.x & 63;
    int w0 = (blockIdx.x * blockDim.x + threadIdx.x) >> 6;
    int nw = (gridDim.x * blockDim.x) >> 6;
    float bias = b[lane];
    for (int ii = w0; ii < N; ii += nw) {
        int i = __builtin_amdgcn_readfirstlane(ii);
        int4 m = meta[i];
        float acc = gather64(hin, wcol, m.x, m.y, __int_as_float(m.z), i, lane);
        out[(ll)i * OUT_C + lane] = acc + bias;
    }
}

// ---------------- launcher ----------------

extern "C" void kernel_launch(void* const* d_in, const int* in_sizes, int n_in,
                              void* d_out, int out_size, void* d_ws, size_t ws_size,
                              hipStream_t stream) {
    const float* x  = (const float*)d_in[0];
    const int*   ei = (const int*)d_in[1];
    const float* W  = (const float*)d_in[2];
    const float* b  = (const float*)d_in[3];
    float* out = (float*)d_out;

    int N = in_sizes[0] / IN_C;      // 65536
    int E = in_sizes[1] / 2;         // 655360
    const int* src = ei;
    const int* dst = ei + E;

    // workspace layout
    size_t cap_slots = (size_t)E + (size_t)PAD * N + 64;      // padded CSR + read guard
    size_t off_total = (size_t)N * 4;                          // cnt at 0, total after
    size_t off_meta  = ((off_total + 4 + 255) & ~(size_t)255); // N int4
    size_t off_dinv  = off_meta + (size_t)N * 16;              // N f32
    size_t off_wcol  = off_dinv + (size_t)N * 4;               // cap_slots int2
    size_t off_y0    = ((off_wcol + cap_slots * 8 + 255) & ~(size_t)255); // N*64 f32
    size_t off_h1    = off_y0 + (size_t)N * OUT_C * 4;         // N*64 f32
    size_t need      = off_h1 + (size_t)N * OUT_C * 4;
    if (ws_size < need) return;      // refuse to scribble OOB

    char* ws = (char*)d_ws;
    int*   cnt_cursor = (int*)(ws);
    int*   total      = (int*)(ws + off_total);
    int4*  meta       = (int4*)(ws + off_meta);
    float* dinv       = (float*)(ws + off_dinv);
    int2*  wcol       = (int2*)(ws + off_wcol);
    float* y0         = (float*)(ws + off_y0);
    float* h1         = (float*)(ws + off_h1);

    hipMemsetAsync(ws, 0, off_total + 4, stream);   // cnt + total

    int ge = (E + 255) / 256;
    int gn = (N + 255) / 256;
    k_count<<<ge, 256, 0, stream>>>(dst, cnt_cursor, E);
    k_alloc<<<gn, 256, 0, stream>>>(cnt_cursor, meta, dinv, wcol, total, N);
    k_fill <<<ge, 256, 0, stream>>>(src, dst, cnt_cursor, dinv, wcol, E);

    k_gemm      <<<2048, 256, 0, stream>>>(x, W, y0, N);
    k_hop64     <<<4096, 256, 0, stream>>>(y0, wcol, meta, h1, N);
    k_hop64_bias<<<4096, 256, 0, stream>>>(h1, wcol, meta, b, out, N);
}

// Round 13
// 251.486 us; speedup vs baseline: 1.5284x; 1.2519x over previous
//
#include <hip/hip_runtime.h>

#define IN_C 128
#define OUT_C 64
#define PAD 8            // degree padded to multiple of 8 -> fixed 8-deep gather groups
typedef long long ll;

// ---------------- CSR build ----------------

__global__ __launch_bounds__(256) void k_count(const int* __restrict__ dst,
                                               int* __restrict__ cnt, int E) {
    int e = blockIdx.x * 256 + threadIdx.x;
    if (e < E) atomicAdd(&cnt[dst[e]], 1);
}

// Allocate padded slot ranges (one atomic per wave via scan), write meta+dinv,
// convert cnt[] into cursor[], and pre-fill pad slots with (col=i, w=0).
__global__ __launch_bounds__(256) void k_alloc(int* __restrict__ cnt_cursor,
                                               int4* __restrict__ meta,
                                               float* __restrict__ dinv,
                                               int2* __restrict__ wcol,
                                               int* __restrict__ total, int N) {
    int i    = blockIdx.x * 256 + threadIdx.x;
    int lane = threadIdx.x & 63;
    int c  = (i < N) ? cnt_cursor[i] : 0;
    int c8 = (c + PAD - 1) & ~(PAD - 1);
    int scan = c8;                       // inclusive wave scan
    #pragma unroll
    for (int d = 1; d < 64; d <<= 1) {
        int t = __shfl_up(scan, d);
        if (lane >= d) scan += t;
    }
    int wave_total = __shfl(scan, 63);
    int base = 0;
    if (lane == 63) base = atomicAdd(total, wave_total);
    base = __shfl(base, 63);
    if (i < N) {
        int s = base + scan - c8;        // exclusive prefix
        float dv = 1.0f / sqrtf((float)(c + 1));   // +1 self-loop
        meta[i] = make_int4(s, c8, __float_as_int(dv), 0);
        dinv[i] = dv;
        cnt_cursor[i] = s;               // becomes fill cursor
        for (int p = s + c; p < s + c8; ++p)       // <=7 pad slots
            wcol[p] = make_int2(i, 0);   // w bits 0 == 0.0f; row i is L1-hot -> cheap
    }
}

// Fill slots with (src, precomputed weight dinv[src]*dinv[dst]).
__global__ __launch_bounds__(256) void k_fill(const int* __restrict__ src,
                                              const int* __restrict__ dst,
                                              int* __restrict__ cursor,
                                              const float* __restrict__ dinv,
                                              int2* __restrict__ wcol, int E) {
    int e = blockIdx.x * 256 + threadIdx.x;
    if (e < E) {
        int s = src[e], d = dst[e];
        int p = atomicAdd(&cursor[d], 1);
        float w = dinv[s] * dinv[d];
        wcol[p] = make_int2(s, __float_as_int(w));
    }
}

// ---------------- GEMM first: y0 = x @ W.T  (no bias; bias added after hops) --------
// Register-tile GEMM, NO shuffles: block = 64 rows; wave owns 16 out-channels;
// lane = row. x staged in LDS (pad 133 -> conflict-free b32 reads); W rows are
// wave-uniform -> scalar (s_load) path; inner loop = pure v_fmac with SGPR operand.

#define GP 133   // LDS row stride (floats); 133%32=5 coprime -> conflict-free
#define OP 69    // out-stage row stride; 69%32=5 coprime

__global__ __launch_bounds__(256) void k_gemm(const float* __restrict__ x,
                                              const float* __restrict__ W,
                                              float* __restrict__ y0, int N) {
    __shared__ float xs[64 * GP];                  // 34048 B
    int tid  = threadIdx.x;
    int lane = tid & 63;
    int wid  = tid >> 6;                           // 0..3
    int r0   = blockIdx.x << 6;                    // 64 rows per block

    // stage 64 rows x 128 cols: coalesced float4 global reads, scalar LDS writes
    #pragma unroll
    for (int k = 0; k < 8; ++k) {
        int fidx = tid + k * 256;                  // 0..2047
        int row  = fidx >> 5;
        int c4   = (fidx & 31) << 2;
        float4 v = *(const float4*)(x + (ll)(r0 + row) * IN_C + c4);
        float* p = &xs[row * GP + c4];
        p[0] = v.x; p[1] = v.y; p[2] = v.z; p[3] = v.w;
    }
    __syncthreads();

    int wo = __builtin_amdgcn_readfirstlane(wid << 4);   // wave's out-channel base (SGPR)
    float acc[16];
    #pragma unroll
    for (int i = 0; i < 16; ++i) acc[i] = 0.f;

    for (int cc = 0; cc < 128; cc += 16) {
        float xv[16];
        #pragma unroll
        for (int k = 0; k < 16; ++k) xv[k] = xs[lane * GP + cc + k];   // conflict-free
        #pragma unroll
        for (int oc = 0; oc < 16; oc += 4) {
            #pragma unroll
            for (int oi = 0; oi < 4; ++oi) {
                const float* wrow = W + (ll)(wo + oc + oi) * IN_C + cc;  // uniform -> s_load
                #pragma unroll
                for (int k = 0; k < 16; ++k)
                    acc[oc + oi] += xv[k] * wrow[k];
            }
        }
    }

    // transpose through LDS for coalesced float4 stores
    __syncthreads();                               // all xs reads done
    float* os = xs;                                // reuse; 64*OP=4416 <= 64*GP
    #pragma unroll
    for (int oi = 0; oi < 16; ++oi) os[lane * OP + wo + oi] = acc[oi];
    __syncthreads();
    #pragma unroll
    for (int k = 0; k < 4; ++k) {
        int fidx = tid + k * 256;                  // 0..1023
        int row  = fidx >> 4;
        int o4   = (fidx & 15) << 2;
        float4 v;
        const float* p = &os[row * OP + o4];
        v.x = p[0]; v.y = p[1]; v.z = p[2]; v.w = p[3];
        *(float4*)(y0 + (ll)(r0 + row) * OUT_C + o4) = v;
    }
}

// ---------------- 64-channel gather core ----------------
// acc = di^2 * h[i][lane] + sum_slots w * h[col][lane];  pad slots have w=0.
// One row = 256 B = exactly one float/lane wave transaction.

template<int G>
__device__ __forceinline__ void g8(float& a0, float& a1, const float* __restrict__ hin,
                                   int2 slot, int lane) {
    int j[8]; float w[8];
    #pragma unroll
    for (int k = 0; k < 8; ++k) {
        j[k] = __builtin_amdgcn_readlane(slot.x, G + k);                    // SGPR
        w[k] = __int_as_float(__builtin_amdgcn_readlane(slot.y, G + k));    // SGPR
    }
    float u[8];
    #pragma unroll
    for (int k = 0; k < 8; ++k) u[k] = hin[(ll)j[k] * OUT_C + lane];        // 8 loads in flight
    #pragma unroll
    for (int k = 0; k < 8; ++k) { if (k & 1) a1 += w[k] * u[k]; else a0 += w[k] * u[k]; }
}

__device__ __forceinline__ void g8dyn(float& a0, float& a1, const float* __restrict__ hin,
                                      int2 slot, int g, int lane) {
    int j[8]; float w[8];
    #pragma unroll
    for (int k = 0; k < 8; ++k) {
        j[k] = __builtin_amdgcn_readlane(slot.x, g + k);
        w[k] = __int_as_float(__builtin_amdgcn_readlane(slot.y, g + k));
    }
    float u[8];
    #pragma unroll
    for (int k = 0; k < 8; ++k) u[k] = hin[(ll)j[k] * OUT_C + lane];
    #pragma unroll
    for (int k = 0; k < 8; ++k) { if (k & 1) a1 += w[k] * u[k]; else a0 += w[k] * u[k]; }
}

__device__ __forceinline__ float gather64(const float* __restrict__ hin,
                                          const int2* __restrict__ wcol,
                                          int s, int c8, float di, int i, int lane) {
    float v  = hin[(ll)i * OUT_C + lane];
    float a0 = di * di * v, a1 = 0.f;
    // c8 is wave-uniform -> scalar branch into straight-line code (97% of nodes)
    if (c8 == 8) {
        int2 sl = wcol[s + lane];                    // +64 guard slots cover lanes 8..63
        g8<0>(a0, a1, hin, sl, lane);
    } else if (c8 == 16) {
        int2 sl = wcol[s + lane];
        g8<0>(a0, a1, hin, sl, lane);                // all 16 gathers independent,
        g8<8>(a0, a1, hin, sl, lane);                // issued back-to-back
    } else if (c8 > 0) {
        for (int base = 0; base < c8; base += 64) {
            int nb = min(64, c8 - base);
            int2 sl = wcol[s + base + lane];
            for (int g = 0; g < nb; g += 8) g8dyn(a0, a1, hin, sl, g, lane);
        }
    }
    return a0 + a1;
}

__global__ __launch_bounds__(256) void k_hop64(const float* __restrict__ hin,
                                               const int2* __restrict__ wcol,
                                               const int4* __restrict__ meta,
                                               float* __restrict__ hout, int N) {
    int lane = threadIdx.x & 63;
    int w0 = (blockIdx.x * blockDim.x + threadIdx.x) >> 6;
    int nw = (gridDim.x * blockDim.x) >> 6;
    for (int ii = w0; ii < N; ii += nw) {
        int i = __builtin_amdgcn_readfirstlane(ii);
        int4 m = meta[i];
        float acc = gather64(hin, wcol, m.x, m.y, __int_as_float(m.z), i, lane);
        hout[(ll)i * OUT_C + lane] = acc;
    }
}

__global__ __launch_bounds__(256) void k_hop64_bias(const float* __restrict__ hin,
                                                    const int2* __restrict__ wcol,
                                                    const int4* __restrict__ meta,
                                                    const float* __restrict__ b,
                                                    float* __restrict__ out, int N) {
    int lane = threadIdx.x & 63;
    int w0 = (blockIdx.x * blockDim.x + threadIdx.x) >> 6;
    int nw = (gridDim.x * blockDim.x) >> 6;
    float bias = b[lane];
    for (int ii = w0; ii < N; ii += nw) {
        int i = __builtin_amdgcn_readfirstlane(ii);
        int4 m = meta[i];
        float acc = gather64(hin, wcol, m.x, m.y, __int_as_float(m.z), i, lane);
        out[(ll)i * OUT_C + lane] = acc + bias;
    }
}

// ---------------- launcher ----------------

extern "C" void kernel_launch(void* const* d_in, const int* in_sizes, int n_in,
                              void* d_out, int out_size, void* d_ws, size_t ws_size,
                              hipStream_t stream) {
    const float* x  = (const float*)d_in[0];
    const int*   ei = (const int*)d_in[1];
    const float* W  = (const float*)d_in[2];
    const float* b  = (const float*)d_in[3];
    float* out = (float*)d_out;

    int N = in_sizes[0] / IN_C;      // 65536
    int E = in_sizes[1] / 2;         // 655360
    const int* src = ei;
    const int* dst = ei + E;

    // workspace layout
    size_t cap_slots = (size_t)E + (size_t)PAD * N + 64;      // padded CSR + read guard
    size_t off_total = (size_t)N * 4;                          // cnt at 0, total after
    size_t off_meta  = ((off_total + 4 + 255) & ~(size_t)255); // N int4
    size_t off_dinv  = off_meta + (size_t)N * 16;              // N f32
    size_t off_wcol  = off_dinv + (size_t)N * 4;               // cap_slots int2
    size_t off_y0    = ((off_wcol + cap_slots * 8 + 255) & ~(size_t)255); // N*64 f32
    size_t off_h1    = off_y0 + (size_t)N * OUT_C * 4;         // N*64 f32
    size_t need      = off_h1 + (size_t)N * OUT_C * 4;
    if (ws_size < need) return;      // refuse to scribble OOB

    char* ws = (char*)d_ws;
    int*   cnt_cursor = (int*)(ws);
    int*   total      = (int*)(ws + off_total);
    int4*  meta       = (int4*)(ws + off_meta);
    float* dinv       = (float*)(ws + off_dinv);
    int2*  wcol       = (int2*)(ws + off_wcol);
    float* y0         = (float*)(ws + off_y0);
    float* h1         = (float*)(ws + off_h1);

    hipMemsetAsync(ws, 0, off_total + 4, stream);   // cnt + total

    int ge = (E + 255) / 256;
    int gn = (N + 255) / 256;
    k_count<<<ge, 256, 0, stream>>>(dst, cnt_cursor, E);
    k_alloc<<<gn, 256, 0, stream>>>(cnt_cursor, meta, dinv, wcol, total, N);
    k_fill <<<ge, 256, 0, stream>>>(src, dst, cnt_cursor, dinv, wcol, E);

    k_gemm      <<<N >> 6, 256, 0, stream>>>(x, W, y0, N);   // N%64==0 (65536)
    k_hop64     <<<4096, 256, 0, stream>>>(y0, wcol, meta, h1, N);
    k_hop64_bias<<<4096, 256, 0, stream>>>(h1, wcol, meta, b, out, N);
}

// Round 15
// 229.503 us; speedup vs baseline: 1.6748x; 1.0958x over previous
//
#include <hip/hip_runtime.h>

#define IN_C 128
#define OUT_C 64
#define PAD 8            // degree padded to multiple of 8 -> fixed 8-deep gather groups
#define GP 132           // LDS row stride (floats); %4==0 for b128 alignment
typedef long long ll;

// ---------------- fused: register-tile GEMM (y0 = x @ W.T)  ||  edge count ----------------
// gemm role (blocks 0..nGemm-1): lane = out-channel; W row lives in 128 VGPRs;
// x rows broadcast from LDS (uniform ds_read_b128); stores coalesced (lane=o).
// count role (blocks nGemm..): plain per-edge atomicAdd histogram. Independent work.

__global__ __launch_bounds__(256) void k_fused_gc(const float* __restrict__ x,
                                                  const float* __restrict__ W,
                                                  float* __restrict__ y0,
                                                  const int* __restrict__ dst,
                                                  int* __restrict__ cnt,
                                                  int nGemm, int E) {
    if ((int)blockIdx.x >= nGemm) {               // ---- count role ----
        int e = (blockIdx.x - nGemm) * 256 + threadIdx.x;
        if (e < E) atomicAdd(&cnt[dst[e]], 1);
        return;
    }
    // ---- gemm role ----
    __shared__ float xs[64 * GP];                 // 33792 B
    int tid  = threadIdx.x;
    int lane = tid & 63;                          // lane == output channel
    int wid  = tid >> 6;                          // 0..3
    int r0   = blockIdx.x << 6;                   // 64 rows per block

    // W row for this lane -> 128 VGPRs (32 x float4). 32KB total, L2-hot across blocks.
    float4 wreg[32];
    const float4* W4 = (const float4*)(W + (ll)lane * IN_C);
    #pragma unroll
    for (int q = 0; q < 32; ++q) wreg[q] = W4[q];

    // stage 64 rows x 128 cols: coalesced float4 global reads, b128 LDS writes
    #pragma unroll
    for (int k = 0; k < 8; ++k) {
        int fidx = tid + k * 256;                 // 0..2047
        int row  = fidx >> 5;
        int c4   = (fidx & 31) << 2;
        float4 v = *(const float4*)(x + (ll)(r0 + row) * IN_C + c4);
        *(float4*)&xs[row * GP + c4] = v;
    }
    __syncthreads();

    // each wave computes 16 rows; per row: 32 uniform b128 reads + 128 fmac
    #pragma unroll
    for (int rr = 0; rr < 16; ++rr) {
        int row = (wid << 4) + rr;                // wave-uniform
        const float4* xq = (const float4*)&xs[row * GP];
        float a0 = 0.f, a1 = 0.f, a2 = 0.f, a3 = 0.f;
        #pragma unroll
        for (int q = 0; q < 32; ++q) {
            float4 xv = xq[q];                    // broadcast (uniform addr)
            float4 wv = wreg[q];
            a0 += xv.x * wv.x; a1 += xv.y * wv.y;
            a2 += xv.z * wv.z; a3 += xv.w * wv.w;
        }
        y0[(ll)(r0 + row) * OUT_C + lane] = (a0 + a1) + (a2 + a3);  // coalesced
    }
}

// ---------------- CSR build ----------------

// Allocate padded slot ranges (one atomic per wave via scan), write meta+dinv,
// convert cnt[] into cursor[], and pre-fill pad slots with (col=i, w=0).
__global__ __launch_bounds__(256) void k_alloc(int* __restrict__ cnt_cursor,
                                               int4* __restrict__ meta,
                                               float* __restrict__ dinv,
                                               int2* __restrict__ wcol,
                                               int* __restrict__ total, int N) {
    int i    = blockIdx.x * 256 + threadIdx.x;
    int lane = threadIdx.x & 63;
    int c  = (i < N) ? cnt_cursor[i] : 0;
    int c8 = (c + PAD - 1) & ~(PAD - 1);
    int scan = c8;                       // inclusive wave scan
    #pragma unroll
    for (int d = 1; d < 64; d <<= 1) {
        int t = __shfl_up(scan, d);
        if (lane >= d) scan += t;
    }
    int wave_total = __shfl(scan, 63);
    int base = 0;
    if (lane == 63) base = atomicAdd(total, wave_total);
    base = __shfl(base, 63);
    if (i < N) {
        int s = base + scan - c8;        // exclusive prefix
        float dv = 1.0f / sqrtf((float)(c + 1));   // +1 self-loop
        meta[i] = make_int4(s, c8, __float_as_int(dv), 0);
        dinv[i] = dv;
        cnt_cursor[i] = s;               // becomes fill cursor
        for (int p = s + c; p < s + c8; ++p)       // <=7 pad slots
            wcol[p] = make_int2(i, 0);   // w bits 0 == 0.0f; row i is L1-hot -> cheap
    }
}

// Fill slots with (src, precomputed weight dinv[src]*dinv[dst]).
__global__ __launch_bounds__(256) void k_fill(const int* __restrict__ src,
                                              const int* __restrict__ dst,
                                              int* __restrict__ cursor,
                                              const float* __restrict__ dinv,
                                              int2* __restrict__ wcol, int E) {
    int e = blockIdx.x * 256 + threadIdx.x;
    if (e < E) {
        int s = src[e], d = dst[e];
        int p = atomicAdd(&cursor[d], 1);
        float w = dinv[s] * dinv[d];
        wcol[p] = make_int2(s, __float_as_int(w));
    }
}

// ---------------- 64-channel gather core ----------------
// acc = di^2 * h[i][lane] + sum_slots w * h[col][lane];  pad slots have w=0.
// One row = 256 B = exactly one float/lane wave transaction.

template<int G>
__device__ __forceinline__ void g8(float& a0, float& a1, const float* __restrict__ hin,
                                   int2 slot, int lane) {
    int j[8]; float w[8];
    #pragma unroll
    for (int k = 0; k < 8; ++k) {
        j[k] = __builtin_amdgcn_readlane(slot.x, G + k);                    // SGPR
        w[k] = __int_as_float(__builtin_amdgcn_readlane(slot.y, G + k));    // SGPR
    }
    float u[8];
    #pragma unroll
    for (int k = 0; k < 8; ++k) u[k] = hin[(ll)j[k] * OUT_C + lane];        // 8 loads in flight
    #pragma unroll
    for (int k = 0; k < 8; ++k) { if (k & 1) a1 += w[k] * u[k]; else a0 += w[k] * u[k]; }
}

__device__ __forceinline__ void g8dyn(float& a0, float& a1, const float* __restrict__ hin,
                                      int2 slot, int g, int lane) {
    int j[8]; float w[8];
    #pragma unroll
    for (int k = 0; k < 8; ++k) {
        j[k] = __builtin_amdgcn_readlane(slot.x, g + k);
        w[k] = __int_as_float(__builtin_amdgcn_readlane(slot.y, g + k));
    }
    float u[8];
    #pragma unroll
    for (int k = 0; k < 8; ++k) u[k] = hin[(ll)j[k] * OUT_C + lane];
    #pragma unroll
    for (int k = 0; k < 8; ++k) { if (k & 1) a1 += w[k] * u[k]; else a0 += w[k] * u[k]; }
}

__device__ __forceinline__ float gather64(const float* __restrict__ hin,
                                          const int2* __restrict__ wcol,
                                          int s, int c8, float di, int i, int lane) {
    float v  = hin[(ll)i * OUT_C + lane];
    float a0 = di * di * v, a1 = 0.f;
    // c8 is wave-uniform -> scalar branch into straight-line code (97% of nodes)
    if (c8 == 8) {
        int2 sl = wcol[s + lane];                    // +64 guard slots cover lanes 8..63
        g8<0>(a0, a1, hin, sl, lane);
    } else if (c8 == 16) {
        int2 sl = wcol[s + lane];
        g8<0>(a0, a1, hin, sl, lane);                // all 16 gathers independent,
        g8<8>(a0, a1, hin, sl, lane);                // issued back-to-back
    } else if (c8 > 0) {
        for (int base = 0; base < c8; base += 64) {
            int nb = min(64, c8 - base);
            int2 sl = wcol[s + base + lane];
            for (int g = 0; g < nb; g += 8) g8dyn(a0, a1, hin, sl, g, lane);
        }
    }
    return a0 + a1;
}

__global__ __launch_bounds__(256) void k_hop64(const float* __restrict__ hin,
                                               const int2* __restrict__ wcol,
                                               const int4* __restrict__ meta,
                                               float* __restrict__ hout, int N) {
    int lane = threadIdx.x & 63;
    int w0 = (blockIdx.x * blockDim.x + threadIdx.x) >> 6;
    int nw = (gridDim.x * blockDim.x) >> 6;
    for (int ii = w0; ii < N; ii += nw) {
        int i = __builtin_amdgcn_readfirstlane(ii);
        int4 m = meta[i];
        float acc = gather64(hin, wcol, m.x, m.y, __int_as_float(m.z), i, lane);
        hout[(ll)i * OUT_C + lane] = acc;
    }
}

__global__ __launch_bounds__(256) void k_hop64_bias(const float* __restrict__ hin,
                                                    const int2* __restrict__ wcol,
                                                    const int4* __restrict__ meta,
                                                    const float* __restrict__ b,
                                                    float* __restrict__ out, int N) {
    int lane = threadIdx.x & 63;
    int w0 = (blockIdx.x * blockDim.x + threadIdx.x) >> 6;
    int nw = (gridDim.x * blockDim.x) >> 6;
    float bias = b[lane];
    for (int ii = w0; ii < N; ii += nw) {
        int i = __builtin_amdgcn_readfirstlane(ii);
        int4 m = meta[i];
        float acc = gather64(hin, wcol, m.x, m.y, __int_as_float(m.z), i, lane);
        out[(ll)i * OUT_C + lane] = acc + bias;
    }
}

// ---------------- launcher ----------------

extern "C" void kernel_launch(void* const* d_in, const int* in_sizes, int n_in,
                              void* d_out, int out_size, void* d_ws, size_t ws_size,
                              hipStream_t stream) {
    const float* x  = (const float*)d_in[0];
    const int*   ei = (const int*)d_in[1];
    const float* W  = (const float*)d_in[2];
    const float* b  = (const float*)d_in[3];
    float* out = (float*)d_out;

    int N = in_sizes[0] / IN_C;      // 65536
    int E = in_sizes[1] / 2;         // 655360
    const int* src = ei;
    const int* dst = ei + E;

    // workspace layout
    size_t cap_slots = (size_t)E + (size_t)PAD * N + 64;      // padded CSR + read guard
    size_t off_total = (size_t)N * 4;                          // cnt at 0, total after
    size_t off_meta  = ((off_total + 4 + 255) & ~(size_t)255); // N int4
    size_t off_dinv  = off_meta + (size_t)N * 16;              // N f32
    size_t off_wcol  = off_dinv + (size_t)N * 4;               // cap_slots int2
    size_t off_y0    = ((off_wcol + cap_slots * 8 + 255) & ~(size_t)255); // N*64 f32
    size_t off_h1    = off_y0 + (size_t)N * OUT_C * 4;         // N*64 f32
    size_t need      = off_h1 + (size_t)N * OUT_C * 4;
    if (ws_size < need) return;      // refuse to scribble OOB

    char* ws = (char*)d_ws;
    int*   cnt_cursor = (int*)(ws);
    int*   total      = (int*)(ws + off_total);
    int4*  meta       = (int4*)(ws + off_meta);
    float* dinv       = (float*)(ws + off_dinv);
    int2*  wcol       = (int2*)(ws + off_wcol);
    float* y0         = (float*)(ws + off_y0);
    float* h1         = (float*)(ws + off_h1);

    hipMemsetAsync(ws, 0, off_total + 4, stream);   // cnt + total

    int nGemm  = N >> 6;                 // 1024 (N%64==0)
    int nCount = (E + 255) / 256;        // 2560
    int gn     = (N + 255) / 256;

    k_fused_gc<<<nGemm + nCount, 256, 0, stream>>>(x, W, y0, dst, cnt_cursor, nGemm, E);
    k_alloc   <<<gn, 256, 0, stream>>>(cnt_cursor, meta, dinv, wcol, total, N);
    k_fill    <<<nCount, 256, 0, stream>>>(src, dst, cnt_cursor, dinv, wcol, E);

    k_hop64     <<<4096, 256, 0, stream>>>(y0, wcol, meta, h1, N);
    k_hop64_bias<<<4096, 256, 0, stream>>>(h1, wcol, meta, b, out, N);
}